// Round 1
// baseline (5359.433 us; speedup 1.0000x reference)
//
#include <hip/hip_runtime.h>
#include <math.h>

#define THREADS 256

// ---------------------------------------------------------------------------
// Transpose (rows x cols) -> (cols x rows). rows = batch chunk (mult of 32).
// ---------------------------------------------------------------------------
__global__ void transpose_k(const float* __restrict__ in, float* __restrict__ out,
                            int rows, int cols) {
  __shared__ float tile[32][33];
  int c0 = blockIdx.x * 32;
  int r0 = blockIdx.y * 32;
  int tx = threadIdx.x, ty = threadIdx.y;  // blockDim = (32,8)
#pragma unroll
  for (int i = 0; i < 4; i++) {
    int r = r0 + ty + i * 8;
    int c = c0 + tx;
    float v = 0.f;
    if (c < cols) v = in[(size_t)r * cols + c];
    tile[ty + i * 8][tx] = v;
  }
  __syncthreads();
#pragma unroll
  for (int i = 0; i < 4; i++) {
    int c = c0 + ty + i * 8;  // output row = original col
    int r = r0 + tx;          // output col = original row
    if (c < cols) out[(size_t)c * rows + r] = tile[tx][ty + i * 8];
  }
}

// ---------------------------------------------------------------------------
// Dense conv, batch-innermost layout.
// in:  (CI, IH, IW, Bc)   w: (CO, CI, KS, KS)   bias: (CO)
// out: (CO, OH, OW, Bc)   out = tanh(conv(in) + bias), stride ST, VALID.
// Each thread: TB batch samples (stride 64) x TC output channels.
// ---------------------------------------------------------------------------
template <int CI, int CO, int IH, int IW, int OH, int OW, int KS, int ST, int TC, int TB>
__global__ void __launch_bounds__(THREADS) conv_dense(
    const float* __restrict__ in, const float* __restrict__ w,
    const float* __restrict__ bias, float* __restrict__ out, int bsh, int nbsh) {
  int tid = blockIdx.x * THREADS + threadIdx.x;
  const int nb = 1 << nbsh;  // Bc / (64*TB)
  int total = (CO / TC) * OH * OW * nb * 64;
  if (tid >= total) return;
  int lane = tid & 63;
  int rest = tid >> 6;
  int wb = rest & (nb - 1);
  rest >>= nbsh;
  int pos = rest % (OH * OW);
  int ocg = rest / (OH * OW);
  int oh = pos / OW, ow = pos % OW;
  int b0 = wb * (64 * TB) + lane;

  float acc[TB][TC];
#pragma unroll
  for (int i = 0; i < TB; i++)
#pragma unroll
    for (int t = 0; t < TC; t++) acc[i][t] = bias[ocg * TC + t];

  const int ih0 = oh * ST, iw0 = ow * ST;
  for (int ci = 0; ci < CI; ci++) {
#pragma unroll
    for (int kh = 0; kh < KS; kh++) {
      float wr[TC][KS];
#pragma unroll
      for (int t = 0; t < TC; t++)
#pragma unroll
        for (int kw = 0; kw < KS; kw++)
          wr[t][kw] = w[(((ocg * TC + t) * CI + ci) * KS + kh) * KS + kw];
#pragma unroll
      for (int kw = 0; kw < KS; kw++) {
        int base = ((ci * IH + ih0 + kh) * IW + iw0 + kw) << bsh;
#pragma unroll
        for (int i = 0; i < TB; i++) {
          float v = in[base + b0 + i * 64];
#pragma unroll
          for (int t = 0; t < TC; t++) acc[i][t] = fmaf(v, wr[t][kw], acc[i][t]);
        }
      }
    }
  }
#pragma unroll
  for (int t = 0; t < TC; t++) {
    int obase = ((ocg * TC + t) * OH * OW + pos) << bsh;
#pragma unroll
    for (int i = 0; i < TB; i++) out[obase + b0 + i * 64] = tanhf(acc[i][t]);
  }
}

// ---------------------------------------------------------------------------
// Locally-connected conv (per-output-position weights), stride 1, VALID.
// in:  (CI, IH, IW, Bc)   w: (OH, OW, CO, CI, KS, KS)   bias: (OH, OW, CO)
// out: (CO, OH, OW, Bc)
// ---------------------------------------------------------------------------
template <int CI, int CO, int IH, int IW, int OH, int OW, int KS, int TC, int TB>
__global__ void __launch_bounds__(THREADS) conv_local(
    const float* __restrict__ in, const float* __restrict__ w,
    const float* __restrict__ bias, float* __restrict__ out, int bsh, int nbsh) {
  int tid = blockIdx.x * THREADS + threadIdx.x;
  const int nb = 1 << nbsh;
  int total = (CO / TC) * OH * OW * nb * 64;
  if (tid >= total) return;
  int lane = tid & 63;
  int rest = tid >> 6;
  int wb = rest & (nb - 1);
  rest >>= nbsh;
  int pos = rest % (OH * OW);
  int ocg = rest / (OH * OW);
  int oh = pos / OW, ow = pos % OW;
  int b0 = wb * (64 * TB) + lane;

  float acc[TB][TC];
#pragma unroll
  for (int i = 0; i < TB; i++)
#pragma unroll
    for (int t = 0; t < TC; t++) acc[i][t] = bias[pos * CO + ocg * TC + t];

  const float* wp = w + (size_t)pos * CO * CI * KS * KS;
  for (int ci = 0; ci < CI; ci++) {
#pragma unroll
    for (int kh = 0; kh < KS; kh++) {
      float wr[TC][KS];
#pragma unroll
      for (int t = 0; t < TC; t++)
#pragma unroll
        for (int kw = 0; kw < KS; kw++)
          wr[t][kw] = wp[(((ocg * TC + t) * CI + ci) * KS + kh) * KS + kw];
#pragma unroll
      for (int kw = 0; kw < KS; kw++) {
        int base = ((ci * IH + oh + kh) * IW + ow + kw) << bsh;
#pragma unroll
        for (int i = 0; i < TB; i++) {
          float v = in[base + b0 + i * 64];
#pragma unroll
          for (int t = 0; t < TC; t++) acc[i][t] = fmaf(v, wr[t][kw], acc[i][t]);
        }
      }
    }
  }
#pragma unroll
  for (int t = 0; t < TC; t++) {
    int obase = ((ocg * TC + t) * OH * OW + pos) << bsh;
#pragma unroll
    for (int i = 0; i < TB; i++) out[obase + b0 + i * 64] = tanhf(acc[i][t]);
  }
}

// ---------------------------------------------------------------------------
// Head: flatten (64,3,3,Bc) -> 576 feats, concat info(8), linear (2,584),
// softmax. Output: out[(b0+b)*2 + {0,1}].
// ---------------------------------------------------------------------------
__global__ void head_k(const float* __restrict__ h5, const float* __restrict__ info,
                       const float* __restrict__ hw, const float* __restrict__ hb,
                       float* __restrict__ out, int Bc, int bsh, int bstart) {
  int b = blockIdx.x * THREADS + threadIdx.x;
  if (b >= Bc) return;
  float l0 = hb[0], l1 = hb[1];
  for (int f = 0; f < 576; f++) {
    float v = h5[(f << bsh) + b];
    l0 = fmaf(v, hw[f], l0);
    l1 = fmaf(v, hw[584 + f], l1);
  }
#pragma unroll
  for (int k = 0; k < 8; k++) {
    float v = info[(size_t)(bstart + b) * 8 + k];
    l0 = fmaf(v, hw[576 + k], l0);
    l1 = fmaf(v, hw[584 + 576 + k], l1);
  }
  float m = fmaxf(l0, l1);
  float e0 = __expf(l0 - m), e1 = __expf(l1 - m);
  float s = e0 + e1;
  out[(size_t)(bstart + b) * 2 + 0] = e0 / s;
  out[(size_t)(bstart + b) * 2 + 1] = e1 / s;
}

// ---------------------------------------------------------------------------

static inline int ilog2(int v) {
  int s = 0;
  while ((1 << s) < v) s++;
  return s;
}

extern "C" void kernel_launch(void* const* d_in, const int* in_sizes, int n_in,
                              void* d_out, int out_size, void* d_ws, size_t ws_size,
                              hipStream_t stream) {
  const float* x = (const float*)d_in[0];
  const float* info = (const float*)d_in[1];
  const float* w1 = (const float*)d_in[2];
  const float* b1 = (const float*)d_in[3];
  const float* w2a = (const float*)d_in[4];
  const float* b2a = (const float*)d_in[5];
  const float* w2b = (const float*)d_in[6];
  const float* b2b = (const float*)d_in[7];
  const float* lw3 = (const float*)d_in[8];
  const float* lb3 = (const float*)d_in[9];
  const float* lw4 = (const float*)d_in[10];
  const float* lb4 = (const float*)d_in[11];
  const float* lw5 = (const float*)d_in[12];
  const float* lb5 = (const float*)d_in[13];
  const float* hw = (const float*)d_in[14];
  const float* hb = (const float*)d_in[15];
  float* out = (float*)d_out;

  const int B = in_sizes[0] / (5 * 60 * 60);  // 2048

  // Per-sample workspace bytes: xT (5*60*60) + bufA (32*29*29) + bufB (64*27*27)
  const size_t PS_XT = 5 * 60 * 60 * 4;    // 72000
  const size_t PS_A = 32 * 29 * 29 * 4;    // 107648
  const size_t PS_B = 64 * 27 * 27 * 4;    // 186624
  const size_t per_sample = PS_XT + PS_A + PS_B;

  int Bc = B;
  while (Bc > 256 && (size_t)Bc * per_sample + 65536 > ws_size) Bc >>= 1;
  const int bsh = ilog2(Bc);
  const int TB = 4;
  const int nbsh = bsh - 8;  // log2(Bc / (64*TB)), Bc >= 256

  float* xT = (float*)d_ws;
  float* bufA = (float*)((char*)d_ws + PS_XT * Bc);
  float* bufB = (float*)((char*)d_ws + (PS_XT + PS_A) * Bc);

  const int nchunks = B / Bc;
  for (int c = 0; c < nchunks; c++) {
    const int bstart = c * Bc;

    // 0) transpose x chunk: (Bc, 18000) -> (18000, Bc)
    {
      dim3 blk(32, 8);
      dim3 grd((18000 + 31) / 32, Bc / 32);
      hipLaunchKernelGGL(transpose_k, grd, blk, 0, stream,
                         x + (size_t)bstart * 18000, xT, Bc, 18000);
    }
    // 1) conv1: 5->32, 60x60 -> 29x29, k3 s2
    {
      int total = (32 / 8) * 29 * 29 * (Bc / 4);
      hipLaunchKernelGGL((conv_dense<5, 32, 60, 60, 29, 29, 3, 2, 8, 4>),
                         dim3((total + THREADS - 1) / THREADS), dim3(THREADS), 0, stream,
                         xT, w1, b1, bufA, bsh, nbsh);
    }
    // 2) conv2a: 32->64, 29x29 -> 27x27, k3 s1
    {
      int total = (64 / 8) * 27 * 27 * (Bc / 4);
      hipLaunchKernelGGL((conv_dense<32, 64, 29, 29, 27, 27, 3, 1, 8, 4>),
                         dim3((total + THREADS - 1) / THREADS), dim3(THREADS), 0, stream,
                         bufA, w2a, b2a, bufB, bsh, nbsh);
    }
    // 3) conv2b: 64->64, 27x27 -> 13x13, k3 s2
    {
      int total = (64 / 8) * 13 * 13 * (Bc / 4);
      hipLaunchKernelGGL((conv_dense<64, 64, 27, 27, 13, 13, 3, 2, 8, 4>),
                         dim3((total + THREADS - 1) / THREADS), dim3(THREADS), 0, stream,
                         bufB, w2b, b2b, bufA, bsh, nbsh);
    }
    // 4) local3: 64->64, 13x13 -> 9x9, k5
    {
      int total = (64 / 8) * 9 * 9 * (Bc / 4);
      hipLaunchKernelGGL((conv_local<64, 64, 13, 13, 9, 9, 5, 8, 4>),
                         dim3((total + THREADS - 1) / THREADS), dim3(THREADS), 0, stream,
                         bufA, lw3, lb3, bufB, bsh, nbsh);
    }
    // 5) local4: 64->64, 9x9 -> 5x5, k5
    {
      int total = (64 / 8) * 5 * 5 * (Bc / 4);
      hipLaunchKernelGGL((conv_local<64, 64, 9, 9, 5, 5, 5, 8, 4>),
                         dim3((total + THREADS - 1) / THREADS), dim3(THREADS), 0, stream,
                         bufB, lw4, lb4, bufA, bsh, nbsh);
    }
    // 6) local5: 64->64, 5x5 -> 3x3, k3
    {
      int total = (64 / 8) * 3 * 3 * (Bc / 4);
      hipLaunchKernelGGL((conv_local<64, 64, 5, 5, 3, 3, 3, 8, 4>),
                         dim3((total + THREADS - 1) / THREADS), dim3(THREADS), 0, stream,
                         bufA, lw5, lb5, bufB, bsh, nbsh);
    }
    // 7) head
    {
      hipLaunchKernelGGL(head_k, dim3((Bc + THREADS - 1) / THREADS), dim3(THREADS), 0,
                         stream, bufB, info, hw, hb, out, Bc, bsh, bstart);
    }
  }
}

// Round 3
// 918.867 us; speedup vs baseline: 5.8327x; 5.8327x over previous
//
#include <hip/hip_runtime.h>
#include <stdint.h>

#define THREADS 256

typedef short bf16x8 __attribute__((ext_vector_type(8)));
typedef float f32x4 __attribute__((ext_vector_type(4)));
typedef unsigned uint2_ __attribute__((ext_vector_type(2)));

__device__ __forceinline__ unsigned short f2bf(float v) {
  unsigned u = __builtin_bit_cast(unsigned, v);
  u = (u + 0x7fff + ((u >> 16) & 1)) >> 16;
  return (unsigned short)u;
}
__device__ __forceinline__ float bf2f(unsigned short h) {
  return __builtin_bit_cast(float, (unsigned)h << 16);
}
__device__ __forceinline__ float fast_tanh(float x) {
  return 1.f - 2.f / (__expf(2.f * x) + 1.f);
}

// ---------------------------------------------------------------------------
// Transpose (rows x cols) -> (cols x rows), fp32. rows = batch chunk (mult 32).
// Produces x in (ci, ih, iw, b) layout for conv1.
// ---------------------------------------------------------------------------
__global__ void transpose_k(const float* __restrict__ in, float* __restrict__ out,
                            int rows, int cols) {
  __shared__ float tile[32][33];
  int c0 = blockIdx.x * 32;
  int r0 = blockIdx.y * 32;
  int tx = threadIdx.x, ty = threadIdx.y;  // blockDim = (32,8)
#pragma unroll
  for (int i = 0; i < 4; i++) {
    int r = r0 + ty + i * 8;
    int c = c0 + tx;
    float v = 0.f;
    if (c < cols) v = in[(size_t)r * cols + c];
    tile[ty + i * 8][tx] = v;
  }
  __syncthreads();
#pragma unroll
  for (int i = 0; i < 4; i++) {
    int c = c0 + ty + i * 8;
    int r = r0 + tx;
    if (c < cols) out[(size_t)c * rows + r] = tile[tx][ty + i * 8];
  }
}

// ---------------------------------------------------------------------------
// conv1 fp32: in (5,60,60,Bc) fp32 -> out (29*29, Bc, 32) bf16, k3 s2, tanh.
// ---------------------------------------------------------------------------
template <int CI, int CO, int IH, int IW, int OH, int OW, int KS, int ST, int TC, int TB>
__global__ void __launch_bounds__(THREADS) conv1_f32(
    const float* __restrict__ in, const float* __restrict__ w,
    const float* __restrict__ bias, unsigned short* __restrict__ out, int Bc, int bsh,
    int nbsh) {
  int tid = blockIdx.x * THREADS + threadIdx.x;
  const int nb = 1 << nbsh;
  int total = (CO / TC) * OH * OW * nb * 64;
  if (tid >= total) return;
  int lane = tid & 63;
  int rest = tid >> 6;
  int wb = rest & (nb - 1);
  rest >>= nbsh;
  int pos = rest % (OH * OW);
  int ocg = rest / (OH * OW);
  int oh = pos / OW, ow = pos % OW;
  int b0 = wb * (64 * TB) + lane;

  float acc[TB][TC];
#pragma unroll
  for (int i = 0; i < TB; i++)
#pragma unroll
    for (int t = 0; t < TC; t++) acc[i][t] = bias[ocg * TC + t];

  const int ih0 = oh * ST, iw0 = ow * ST;
  for (int ci = 0; ci < CI; ci++) {
#pragma unroll
    for (int kh = 0; kh < KS; kh++) {
      float wr[TC][KS];
#pragma unroll
      for (int t = 0; t < TC; t++)
#pragma unroll
        for (int kw = 0; kw < KS; kw++)
          wr[t][kw] = w[(((ocg * TC + t) * CI + ci) * KS + kh) * KS + kw];
#pragma unroll
      for (int kw = 0; kw < KS; kw++) {
        int base = ((ci * IH + ih0 + kh) * IW + iw0 + kw) << bsh;
#pragma unroll
        for (int i = 0; i < TB; i++) {
          float v = in[base + b0 + i * 64];
#pragma unroll
          for (int t = 0; t < TC; t++) acc[i][t] = fmaf(v, wr[t][kw], acc[i][t]);
        }
      }
    }
  }
#pragma unroll
  for (int i = 0; i < TB; i++) {
    bf16x8 o;
#pragma unroll
    for (int t = 0; t < TC; t++) o[t] = (short)f2bf(fast_tanh(acc[i][t]));
    int b = b0 + i * 64;
    *(bf16x8*)(out + ((size_t)pos * Bc + b) * CO + ocg * TC) = o;
  }
}

// ---------------------------------------------------------------------------
// Weight pre-pack into MFMA A-fragment order (bf16).
// src w: (npos*64, CI, KS, KS) fp32   (npos=1 for dense convs)
// dst wp: flat[pos][s][mt][lane][e], value = W[co=mt*16+(lane&15)]
//                                          [k = s*32 + (lane>>4)*8 + e]
// k-order: k = (kh*KS+kw)*CI + ci  (ci innermost).
// ---------------------------------------------------------------------------
template <int CI, int KS>
__global__ void __launch_bounds__(THREADS) pack_w(const float* __restrict__ w,
                                                  unsigned short* __restrict__ wp,
                                                  int npos) {
  constexpr int K = CI * KS * KS;
  constexpr int S = K / 32;
  int idx = blockIdx.x * THREADS + threadIdx.x;
  int total = npos * S * 2048;
  if (idx >= total) return;
  int e = idx & 7;
  int lane = (idx >> 3) & 63;
  int mt = (idx >> 9) & 3;
  int rest = idx >> 11;  // pos*S + s
  int s = rest % S, pos = rest / S;
  int co = mt * 16 + (lane & 15);
  int k = s * 32 + (lane >> 4) * 8 + e;
  int tap = k / CI, ci = k % CI;
  int kh = tap / KS, kw = tap % KS;
  float v = w[((((size_t)pos * 64 + co) * CI + ci) * KS + kh) * KS + kw];
  wp[idx] = f2bf(v);
}

// ---------------------------------------------------------------------------
// MFMA conv (dense or locally-connected), bf16 in/out, fp32 accum, tanh.
// X: (IH*IW, Bc, CI) bf16   Wp: packed   Y: (OH*OW, Bc, 64) bf16
// Block: 256 thr = 4 waves; one output position x 64 co x 128 batch.
// A-frags from packed global; B-frags direct 16B global loads (same phi(g,e)
// k-order as pack_w -> hardware k-mapping cancels).
// ---------------------------------------------------------------------------
template <int CI, int IH, int IW, int OH, int OW, int KS, int ST, bool LOCAL>
__global__ void __launch_bounds__(256) conv_mfma(
    const unsigned short* __restrict__ X, const unsigned short* __restrict__ Wp,
    const float* __restrict__ bias, unsigned short* __restrict__ Y, int Bc) {
  constexpr int K = CI * KS * KS;
  constexpr int S = K / 32;
  constexpr int NPOS = OH * OW;

  const int tid = threadIdx.x;
  const int lane = tid & 63;
  const int wu = tid >> 6;
  const int n = lane & 15, g = lane >> 4;

  const int pos = blockIdx.x % NPOS;
  const int btile = blockIdx.x / NPOS;
  const int oh = pos / OW, ow = pos % OW;
  const int b0 = btile * 128 + wu * 32;

  const unsigned short* Wpp = Wp + (LOCAL ? (size_t)pos * (S * 2048) : 0);

  f32x4 acc[4][2] = {};

  const int bA = b0 + n;
#pragma unroll 2
  for (int s = 0; s < S; s++) {
    const int tap = (s * 32) / CI;
    const int ci0 = (s * 32) % CI + g * 8;
    const int kh = tap / KS, kw = tap % KS;
    const int pin = (oh * ST + kh) * IW + (ow * ST + kw);
    const unsigned short* xb = X + ((size_t)pin * Bc + bA) * CI + ci0;
    bf16x8 bfr[2];
    bfr[0] = *(const bf16x8*)xb;
    bfr[1] = *(const bf16x8*)(xb + 16 * CI);
    bf16x8 af[4];
#pragma unroll
    for (int mt = 0; mt < 4; mt++)
      af[mt] = *(const bf16x8*)(Wpp + ((size_t)((s * 4 + mt) * 64 + lane) << 3));
#pragma unroll
    for (int mt = 0; mt < 4; mt++)
#pragma unroll
      for (int nf = 0; nf < 2; nf++)
        acc[mt][nf] =
            __builtin_amdgcn_mfma_f32_16x16x32_bf16(af[mt], bfr[nf], acc[mt][nf], 0, 0, 0);
  }

  // epilogue: D col=lane&15 (batch), row=(lane>>4)*4+reg (co)
#pragma unroll
  for (int mt = 0; mt < 4; mt++) {
#pragma unroll
    for (int nf = 0; nf < 2; nf++) {
      unsigned short o[4];
#pragma unroll
      for (int r = 0; r < 4; r++) {
        const int co = mt * 16 + g * 4 + r;
        const float bv = LOCAL ? bias[pos * 64 + co] : bias[co];
        o[r] = f2bf(fast_tanh(acc[mt][nf][r] + bv));
      }
      const int b = b0 + nf * 16 + n;
      uint2_ pk;
      pk[0] = (unsigned)o[0] | ((unsigned)o[1] << 16);
      pk[1] = (unsigned)o[2] | ((unsigned)o[3] << 16);
      *(uint2_*)(Y + ((size_t)pos * Bc + b) * 64 + mt * 16 + g * 4) = pk;
    }
  }
}

// ---------------------------------------------------------------------------
// Head: h5 (9, Bc, 64) bf16; f = co*9 + pos. concat info(8), linear, softmax.
// ---------------------------------------------------------------------------
__global__ void head_k(const unsigned short* __restrict__ h5,
                       const float* __restrict__ info, const float* __restrict__ hw,
                       const float* __restrict__ hb, float* __restrict__ out, int Bc,
                       int bstart) {
  int b = blockIdx.x * THREADS + threadIdx.x;
  if (b >= Bc) return;
  float l0 = hb[0], l1 = hb[1];
  for (int pos = 0; pos < 9; pos++) {
#pragma unroll
    for (int co = 0; co < 64; co++) {
      float v = bf2f(h5[((size_t)pos * Bc + b) * 64 + co]);
      int f = co * 9 + pos;
      l0 = fmaf(v, hw[f], l0);
      l1 = fmaf(v, hw[584 + f], l1);
    }
  }
#pragma unroll
  for (int k = 0; k < 8; k++) {
    float v = info[(size_t)(bstart + b) * 8 + k];
    l0 = fmaf(v, hw[576 + k], l0);
    l1 = fmaf(v, hw[584 + 576 + k], l1);
  }
  float m = fmaxf(l0, l1);
  float e0 = __expf(l0 - m), e1 = __expf(l1 - m);
  float s = e0 + e1;
  out[(size_t)(bstart + b) * 2 + 0] = e0 / s;
  out[(size_t)(bstart + b) * 2 + 1] = e1 / s;
}

// ---------------------------------------------------------------------------

static inline int ilog2(int v) {
  int s = 0;
  while ((1 << s) < v) s++;
  return s;
}

extern "C" void kernel_launch(void* const* d_in, const int* in_sizes, int n_in,
                              void* d_out, int out_size, void* d_ws, size_t ws_size,
                              hipStream_t stream) {
  const float* x = (const float*)d_in[0];
  const float* info = (const float*)d_in[1];
  const float* w1 = (const float*)d_in[2];
  const float* b1 = (const float*)d_in[3];
  const float* w2a = (const float*)d_in[4];
  const float* b2a = (const float*)d_in[5];
  const float* w2b = (const float*)d_in[6];
  const float* b2b = (const float*)d_in[7];
  const float* lw3 = (const float*)d_in[8];
  const float* lb3 = (const float*)d_in[9];
  const float* lw4 = (const float*)d_in[10];
  const float* lb4 = (const float*)d_in[11];
  const float* lw5 = (const float*)d_in[12];
  const float* lb5 = (const float*)d_in[13];
  const float* hw = (const float*)d_in[14];
  const float* hb = (const float*)d_in[15];
  float* out = (float*)d_out;

  const int B = in_sizes[0] / 18000;  // 2048

  // packed weights at ws start (S = K/32, each step = 2048 ushorts)
  const size_t SZ2A = 9ull * 2048, SZ2B = 18ull * 2048, SZ3 = 81ull * 50 * 2048,
               SZ4 = 25ull * 50 * 2048, SZ5 = 9ull * 18 * 2048;
  unsigned short* wp2a = (unsigned short*)d_ws;
  unsigned short* wp2b = wp2a + SZ2A;
  unsigned short* wp3 = wp2b + SZ2B;
  unsigned short* wp4 = wp3 + SZ3;
  unsigned short* wp5 = wp4 + SZ4;
  size_t wp_bytes = (SZ2A + SZ2B + SZ3 + SZ4 + SZ5) * 2;
  wp_bytes = (wp_bytes + 255) & ~(size_t)255;

  // per-sample chunk buffers: xT fp32 72000B, bufA bf16 53824B, bufB bf16 93312B
  const size_t per_sample = 72000 + 53824 + 93312;
  int Bc = B;
  while (Bc > 256 && wp_bytes + (size_t)Bc * per_sample + 4096 > ws_size) Bc >>= 1;
  const int bsh = ilog2(Bc);
  const int nbsh = bsh - 8;
  const int nbt = Bc / 128;

  float* xT = (float*)((char*)d_ws + wp_bytes);
  unsigned short* bufA = (unsigned short*)((char*)d_ws + wp_bytes + (size_t)Bc * 72000);
  unsigned short* bufB =
      (unsigned short*)((char*)d_ws + wp_bytes + (size_t)Bc * (72000 + 53824));

  // one-time weight packing (deterministic each launch)
  hipLaunchKernelGGL((pack_w<32, 3>), dim3((SZ2A + 255) / 256), dim3(THREADS), 0, stream,
                     w2a, wp2a, 1);
  hipLaunchKernelGGL((pack_w<64, 3>), dim3((SZ2B + 255) / 256), dim3(THREADS), 0, stream,
                     w2b, wp2b, 1);
  hipLaunchKernelGGL((pack_w<64, 5>), dim3((SZ3 + 255) / 256), dim3(THREADS), 0, stream,
                     lw3, wp3, 81);
  hipLaunchKernelGGL((pack_w<64, 5>), dim3((SZ4 + 255) / 256), dim3(THREADS), 0, stream,
                     lw4, wp4, 25);
  hipLaunchKernelGGL((pack_w<64, 3>), dim3((SZ5 + 255) / 256), dim3(THREADS), 0, stream,
                     lw5, wp5, 9);

  const int nchunks = B / Bc;
  for (int c = 0; c < nchunks; c++) {
    const int bstart = c * Bc;

    {  // x chunk transpose: (Bc, 18000) -> (18000, Bc)
      dim3 blk(32, 8);
      dim3 grd((18000 + 31) / 32, Bc / 32);
      hipLaunchKernelGGL(transpose_k, grd, blk, 0, stream, x + (size_t)bstart * 18000,
                         xT, Bc, 18000);
    }
    {  // conv1 fp32: 5->32, 60x60 -> 29x29, k3 s2; out (841, Bc, 32)
      int total = (32 / 8) * 29 * 29 * (Bc / 4);
      hipLaunchKernelGGL((conv1_f32<5, 32, 60, 60, 29, 29, 3, 2, 8, 4>),
                         dim3((total + THREADS - 1) / THREADS), dim3(THREADS), 0, stream,
                         xT, w1, b1, bufA, Bc, bsh, nbsh);
    }
    // conv2a: 32->64, 29x29 -> 27x27, k3 s1
    hipLaunchKernelGGL((conv_mfma<32, 29, 29, 27, 27, 3, 1, false>),
                       dim3(729 * nbt), dim3(256), 0, stream, bufA, wp2a, b2a, bufB, Bc);
    // conv2b: 64->64, 27x27 -> 13x13, k3 s2
    hipLaunchKernelGGL((conv_mfma<64, 27, 27, 13, 13, 3, 2, false>),
                       dim3(169 * nbt), dim3(256), 0, stream, bufB, wp2b, b2b, bufA, Bc);
    // local3: 64->64, 13x13 -> 9x9, k5
    hipLaunchKernelGGL((conv_mfma<64, 13, 13, 9, 9, 5, 1, true>),
                       dim3(81 * nbt), dim3(256), 0, stream, bufA, wp3, lb3, bufB, Bc);
    // local4: 64->64, 9x9 -> 5x5, k5
    hipLaunchKernelGGL((conv_mfma<64, 9, 9, 5, 5, 5, 1, true>),
                       dim3(25 * nbt), dim3(256), 0, stream, bufB, wp4, lb4, bufA, Bc);
    // local5: 64->64, 5x5 -> 3x3, k3
    hipLaunchKernelGGL((conv_mfma<64, 5, 5, 3, 3, 3, 1, true>),
                       dim3(9 * nbt), dim3(256), 0, stream, bufA, wp5, lb5, bufB, Bc);
    // head
    hipLaunchKernelGGL(head_k, dim3((Bc + THREADS - 1) / THREADS), dim3(THREADS), 0,
                       stream, bufB, info, hw, hb, out, Bc, bstart);
  }
}

// Round 4
// 843.466 us; speedup vs baseline: 6.3541x; 1.0894x over previous
//
#include <hip/hip_runtime.h>
#include <stdint.h>

#define THREADS 256

typedef short bf16x8 __attribute__((ext_vector_type(8)));
typedef float f32x4 __attribute__((ext_vector_type(4)));
typedef unsigned uint2_ __attribute__((ext_vector_type(2)));
typedef unsigned short ushort4_ __attribute__((ext_vector_type(4)));

__device__ __forceinline__ unsigned short f2bf(float v) {
  unsigned u = __builtin_bit_cast(unsigned, v);
  u = (u + 0x7fff + ((u >> 16) & 1)) >> 16;
  return (unsigned short)u;
}
__device__ __forceinline__ float bf2f(unsigned short h) {
  return __builtin_bit_cast(float, (unsigned)h << 16);
}
__device__ __forceinline__ float fast_tanh(float x) {
  return 1.f - 2.f / (__expf(2.f * x) + 1.f);
}

// ---------------------------------------------------------------------------
// Transpose+cast: (rows=Bc, cols=18000) f32 -> (cols, rows) bf16.
// 64x64 tiles, block (64,8). 256B coalesced reads, 128B stores.
// ---------------------------------------------------------------------------
__global__ void __launch_bounds__(512) transpose_cast_k(
    const float* __restrict__ in, unsigned short* __restrict__ out, int rows, int cols) {
  __shared__ float tile[64][65];
  int c0 = blockIdx.x * 64;
  int r0 = blockIdx.y * 64;
  int tx = threadIdx.x, ty = threadIdx.y;  // (64,8)
#pragma unroll
  for (int i = 0; i < 8; i++) {
    int r = r0 + ty + i * 8;
    int c = c0 + tx;
    float v = (c < cols) ? in[(size_t)r * cols + c] : 0.f;
    tile[ty + i * 8][tx] = v;
  }
  __syncthreads();
#pragma unroll
  for (int i = 0; i < 8; i++) {
    int c = c0 + ty + i * 8;
    int r = r0 + tx;
    if (c < cols) out[(size_t)c * rows + r] = f2bf(tile[tx][ty + i * 8]);
  }
}

// ---------------------------------------------------------------------------
// conv1: xT (5,60,60,Bc) bf16 -> out (29*29, Bc, 32) bf16, k3 s2, tanh.
// Block = 4 waves; wave = co-group (8 co), lane = 4 contiguous batches.
// All 4 waves read identical x words (L1 broadcast). Grid pos-major.
// ---------------------------------------------------------------------------
template <int CI, int CO, int IH, int IW, int OH, int OW, int KS, int ST>
__global__ void __launch_bounds__(256) conv1_bf16(
    const unsigned short* __restrict__ xT, const float* __restrict__ w,
    const float* __restrict__ bias, unsigned short* __restrict__ out, int Bc) {
  const int tid = threadIdx.x;
  const int lane = tid & 63;
  const int wu = tid >> 6;  // co-group
  const int pos = blockIdx.x % (OH * OW);
  const int bblk = blockIdx.x / (OH * OW);
  const int oh = pos / OW, ow = pos % OW;
  const int b0 = bblk * 256 + lane * 4;

  float acc[4][8];
#pragma unroll
  for (int i = 0; i < 4; i++)
#pragma unroll
    for (int t = 0; t < 8; t++) acc[i][t] = bias[wu * 8 + t];

  const int ih0 = oh * ST, iw0 = ow * ST;
  for (int ci = 0; ci < CI; ci++) {
#pragma unroll
    for (int kh = 0; kh < KS; kh++) {
      float wr[8][KS];
#pragma unroll
      for (int t = 0; t < 8; t++)
#pragma unroll
        for (int kw = 0; kw < KS; kw++)
          wr[t][kw] = w[(((wu * 8 + t) * CI + ci) * KS + kh) * KS + kw];
#pragma unroll
      for (int kw = 0; kw < KS; kw++) {
        const unsigned short* xp =
            xT + (size_t)((ci * IH + ih0 + kh) * IW + iw0 + kw) * Bc + b0;
        ushort4_ v4 = *(const ushort4_*)xp;
        float xv[4] = {bf2f(v4[0]), bf2f(v4[1]), bf2f(v4[2]), bf2f(v4[3])};
#pragma unroll
        for (int i = 0; i < 4; i++)
#pragma unroll
          for (int t = 0; t < 8; t++) acc[i][t] = fmaf(xv[i], wr[t][kw], acc[i][t]);
      }
    }
  }
#pragma unroll
  for (int i = 0; i < 4; i++) {
    bf16x8 o;
#pragma unroll
    for (int t = 0; t < 8; t++) o[t] = (short)f2bf(fast_tanh(acc[i][t]));
    *(bf16x8*)(out + ((size_t)pos * Bc + b0 + i) * CO + wu * 8) = o;
  }
}

// ---------------------------------------------------------------------------
// Weight pre-pack into MFMA A-fragment order (bf16).
// dst wp: flat[pos][s][mt][lane][e], value = W[co=mt*16+(lane&15)]
//                                          [k = s*32 + (lane>>4)*8 + e]
// k-order: k = (kh*KS+kw)*CI + ci  (ci innermost).
// ---------------------------------------------------------------------------
template <int CI, int KS>
__global__ void __launch_bounds__(THREADS) pack_w(const float* __restrict__ w,
                                                  unsigned short* __restrict__ wp,
                                                  int npos) {
  constexpr int K = CI * KS * KS;
  constexpr int S = K / 32;
  int idx = blockIdx.x * THREADS + threadIdx.x;
  int total = npos * S * 2048;
  if (idx >= total) return;
  int e = idx & 7;
  int lane = (idx >> 3) & 63;
  int mt = (idx >> 9) & 3;
  int rest = idx >> 11;  // pos*S + s
  int s = rest % S, pos = rest / S;
  int co = mt * 16 + (lane & 15);
  int k = s * 32 + (lane >> 4) * 8 + e;
  int tap = k / CI, ci = k % CI;
  int kh = tap / KS, kw = tap % KS;
  float v = w[((((size_t)pos * 64 + co) * CI + ci) * KS + kh) * KS + kw];
  wp[idx] = f2bf(v);
}

// ---------------------------------------------------------------------------
// MFMA conv (dense or locally-connected), bf16 in/out, fp32 accum, tanh.
// X: (IH*IW, Bc, CI) bf16   Wp: packed   Y: (OH*OW, Bc, 64) bf16
// Block: 256 thr = 4 waves; one output position x 64 co x 128 batch.
// ---------------------------------------------------------------------------
template <int CI, int IH, int IW, int OH, int OW, int KS, int ST, bool LOCAL>
__global__ void __launch_bounds__(256) conv_mfma(
    const unsigned short* __restrict__ X, const unsigned short* __restrict__ Wp,
    const float* __restrict__ bias, unsigned short* __restrict__ Y, int Bc) {
  constexpr int K = CI * KS * KS;
  constexpr int S = K / 32;
  constexpr int NPOS = OH * OW;

  const int tid = threadIdx.x;
  const int lane = tid & 63;
  const int wu = tid >> 6;
  const int n = lane & 15, g = lane >> 4;

  const int pos = blockIdx.x % NPOS;
  const int btile = blockIdx.x / NPOS;
  const int oh = pos / OW, ow = pos % OW;
  const int b0 = btile * 128 + wu * 32;

  const unsigned short* Wpp = Wp + (LOCAL ? (size_t)pos * (S * 2048) : 0);

  f32x4 acc[4][2] = {};

  const int bA = b0 + n;
#pragma unroll 2
  for (int s = 0; s < S; s++) {
    const int tap = (s * 32) / CI;
    const int ci0 = (s * 32) % CI + g * 8;
    const int kh = tap / KS, kw = tap % KS;
    const int pin = (oh * ST + kh) * IW + (ow * ST + kw);
    const unsigned short* xb = X + ((size_t)pin * Bc + bA) * CI + ci0;
    bf16x8 bfr[2];
    bfr[0] = *(const bf16x8*)xb;
    bfr[1] = *(const bf16x8*)(xb + 16 * CI);
    bf16x8 af[4];
#pragma unroll
    for (int mt = 0; mt < 4; mt++)
      af[mt] = *(const bf16x8*)(Wpp + ((size_t)((s * 4 + mt) * 64 + lane) << 3));
#pragma unroll
    for (int mt = 0; mt < 4; mt++)
#pragma unroll
      for (int nf = 0; nf < 2; nf++)
        acc[mt][nf] =
            __builtin_amdgcn_mfma_f32_16x16x32_bf16(af[mt], bfr[nf], acc[mt][nf], 0, 0, 0);
  }

  // epilogue: D col=lane&15 (batch), row=(lane>>4)*4+reg (co)
#pragma unroll
  for (int mt = 0; mt < 4; mt++) {
#pragma unroll
    for (int nf = 0; nf < 2; nf++) {
      unsigned short o[4];
#pragma unroll
      for (int r = 0; r < 4; r++) {
        const int co = mt * 16 + g * 4 + r;
        const float bv = LOCAL ? bias[pos * 64 + co] : bias[co];
        o[r] = f2bf(fast_tanh(acc[mt][nf][r] + bv));
      }
      const int b = b0 + nf * 16 + n;
      uint2_ pk;
      pk[0] = (unsigned)o[0] | ((unsigned)o[1] << 16);
      pk[1] = (unsigned)o[2] | ((unsigned)o[3] << 16);
      *(uint2_*)(Y + ((size_t)pos * Bc + b) * 64 + mt * 16 + g * 4) = pk;
    }
  }
}

// ---------------------------------------------------------------------------
// Head: h5 (9, Bc, 64) bf16; f = co*9 + pos. concat info(8), linear, softmax.
// ---------------------------------------------------------------------------
__global__ void head_k(const unsigned short* __restrict__ h5,
                       const float* __restrict__ info, const float* __restrict__ hw,
                       const float* __restrict__ hb, float* __restrict__ out, int Bc,
                       int bstart) {
  int b = blockIdx.x * THREADS + threadIdx.x;
  if (b >= Bc) return;
  float l0 = hb[0], l1 = hb[1];
  for (int pos = 0; pos < 9; pos++) {
#pragma unroll
    for (int co = 0; co < 64; co++) {
      float v = bf2f(h5[((size_t)pos * Bc + b) * 64 + co]);
      int f = co * 9 + pos;
      l0 = fmaf(v, hw[f], l0);
      l1 = fmaf(v, hw[584 + f], l1);
    }
  }
#pragma unroll
  for (int k = 0; k < 8; k++) {
    float v = info[(size_t)(bstart + b) * 8 + k];
    l0 = fmaf(v, hw[576 + k], l0);
    l1 = fmaf(v, hw[584 + 576 + k], l1);
  }
  float m = fmaxf(l0, l1);
  float e0 = __expf(l0 - m), e1 = __expf(l1 - m);
  float s = e0 + e1;
  out[(size_t)(bstart + b) * 2 + 0] = e0 / s;
  out[(size_t)(bstart + b) * 2 + 1] = e1 / s;
}

// ---------------------------------------------------------------------------

extern "C" void kernel_launch(void* const* d_in, const int* in_sizes, int n_in,
                              void* d_out, int out_size, void* d_ws, size_t ws_size,
                              hipStream_t stream) {
  const float* x = (const float*)d_in[0];
  const float* info = (const float*)d_in[1];
  const float* w1 = (const float*)d_in[2];
  const float* b1 = (const float*)d_in[3];
  const float* w2a = (const float*)d_in[4];
  const float* b2a = (const float*)d_in[5];
  const float* w2b = (const float*)d_in[6];
  const float* b2b = (const float*)d_in[7];
  const float* lw3 = (const float*)d_in[8];
  const float* lb3 = (const float*)d_in[9];
  const float* lw4 = (const float*)d_in[10];
  const float* lb4 = (const float*)d_in[11];
  const float* lw5 = (const float*)d_in[12];
  const float* lb5 = (const float*)d_in[13];
  const float* hw = (const float*)d_in[14];
  const float* hb = (const float*)d_in[15];
  float* out = (float*)d_out;

  const int B = in_sizes[0] / 18000;  // 2048

  // packed weights at ws start (S = K/32, each step = 2048 ushorts)
  const size_t SZ2A = 9ull * 2048, SZ2B = 18ull * 2048, SZ3 = 81ull * 50 * 2048,
               SZ4 = 25ull * 50 * 2048, SZ5 = 9ull * 18 * 2048;
  unsigned short* wp2a = (unsigned short*)d_ws;
  unsigned short* wp2b = wp2a + SZ2A;
  unsigned short* wp3 = wp2b + SZ2B;
  unsigned short* wp4 = wp3 + SZ3;
  unsigned short* wp5 = wp4 + SZ4;
  size_t wp_bytes = (SZ2A + SZ2B + SZ3 + SZ4 + SZ5) * 2;
  wp_bytes = (wp_bytes + 255) & ~(size_t)255;

  // per-sample chunk buffers: xT bf16 36000B, bufA bf16 53824B, bufB bf16 93312B
  const size_t per_sample = 36000 + 53824 + 93312;
  int Bc = B;
  while (Bc > 256 && wp_bytes + (size_t)Bc * per_sample + 4096 > ws_size) Bc >>= 1;
  const int nbt = Bc / 128;

  unsigned short* xT = (unsigned short*)((char*)d_ws + wp_bytes);
  unsigned short* bufA = (unsigned short*)((char*)d_ws + wp_bytes + (size_t)Bc * 36000);
  unsigned short* bufB =
      (unsigned short*)((char*)d_ws + wp_bytes + (size_t)Bc * (36000 + 53824));

  // one-time weight packing (deterministic each launch)
  hipLaunchKernelGGL((pack_w<32, 3>), dim3((SZ2A + 255) / 256), dim3(THREADS), 0, stream,
                     w2a, wp2a, 1);
  hipLaunchKernelGGL((pack_w<64, 3>), dim3((SZ2B + 255) / 256), dim3(THREADS), 0, stream,
                     w2b, wp2b, 1);
  hipLaunchKernelGGL((pack_w<64, 5>), dim3((SZ3 + 255) / 256), dim3(THREADS), 0, stream,
                     lw3, wp3, 81);
  hipLaunchKernelGGL((pack_w<64, 5>), dim3((SZ4 + 255) / 256), dim3(THREADS), 0, stream,
                     lw4, wp4, 25);
  hipLaunchKernelGGL((pack_w<64, 3>), dim3((SZ5 + 255) / 256), dim3(THREADS), 0, stream,
                     lw5, wp5, 9);

  const int nchunks = B / Bc;
  for (int c = 0; c < nchunks; c++) {
    const int bstart = c * Bc;

    {  // x chunk transpose+cast: (Bc, 18000) f32 -> (18000, Bc) bf16
      dim3 blk(64, 8);
      dim3 grd((18000 + 63) / 64, Bc / 64);
      hipLaunchKernelGGL(transpose_cast_k, grd, blk, 0, stream,
                         x + (size_t)bstart * 18000, xT, Bc, 18000);
    }
    // conv1: 5->32, 60x60 -> 29x29, k3 s2; out (841, Bc, 32)
    hipLaunchKernelGGL((conv1_bf16<5, 32, 60, 60, 29, 29, 3, 2>),
                       dim3(841 * (Bc / 256)), dim3(256), 0, stream, xT, w1, b1, bufA,
                       Bc);
    // conv2a: 32->64, 29x29 -> 27x27, k3 s1
    hipLaunchKernelGGL((conv_mfma<32, 29, 29, 27, 27, 3, 1, false>),
                       dim3(729 * nbt), dim3(256), 0, stream, bufA, wp2a, b2a, bufB, Bc);
    // conv2b: 64->64, 27x27 -> 13x13, k3 s2
    hipLaunchKernelGGL((conv_mfma<64, 27, 27, 13, 13, 3, 2, false>),
                       dim3(169 * nbt), dim3(256), 0, stream, bufB, wp2b, b2b, bufA, Bc);
    // local3: 64->64, 13x13 -> 9x9, k5
    hipLaunchKernelGGL((conv_mfma<64, 13, 13, 9, 9, 5, 1, true>),
                       dim3(81 * nbt), dim3(256), 0, stream, bufA, wp3, lb3, bufB, Bc);
    // local4: 64->64, 9x9 -> 5x5, k5
    hipLaunchKernelGGL((conv_mfma<64, 9, 9, 5, 5, 5, 1, true>),
                       dim3(25 * nbt), dim3(256), 0, stream, bufB, wp4, lb4, bufA, Bc);
    // local5: 64->64, 5x5 -> 3x3, k3
    hipLaunchKernelGGL((conv_mfma<64, 5, 5, 3, 3, 3, 1, true>),
                       dim3(9 * nbt), dim3(256), 0, stream, bufA, wp5, lb5, bufB, Bc);
    // head
    hipLaunchKernelGGL(head_k, dim3((Bc + THREADS - 1) / THREADS), dim3(THREADS), 0,
                       stream, bufB, info, hw, hb, out, Bc, bstart);
  }
}